// Round 2
// baseline (651.256 us; speedup 1.0000x reference)
//
#include <hip/hip_runtime.h>

#define E_EDGES   800000
#define NN_NODES  50000
#define NODE_DIM  128
#define EDGE_DIM  64
#define KDIM      320
#define NTOT      256      // val(128) || gate(128)
#define BM        64       // edges per block (new main)
#define OBM       128      // edges per block (fallback main)
#define BN        64       // nodes per block (pcompute)
#define SA        72       // LDS row stride (f16) for K=64 tile
#define SX        136      // LDS row stride (f16) for K=128 tile
#define THREADS   512

typedef _Float16 half8 __attribute__((ext_vector_type(8)));
typedef float    f32x4 __attribute__((ext_vector_type(4)));

__device__ __forceinline__ unsigned short f2h(float f) {
    _Float16 h = (_Float16)f;
    return __builtin_bit_cast(unsigned short, h);
}
__device__ __forceinline__ float h2f(unsigned short u) {
    return (float)__builtin_bit_cast(_Float16, u);
}

// ============================ NEW PATH ============================

// ---- cast W_val||W_mul (256 x 320) fp32 -> f16 ----
__global__ void cast_w(const float* __restrict__ wv,
                       const float* __restrict__ wm,
                       unsigned short* __restrict__ Wc) {
    const int n4h = (NODE_DIM * KDIM) / 4;   // 10240 float4 units per matrix
    int i = blockIdx.x * blockDim.x + threadIdx.x;
    if (i >= 2 * n4h) return;
    const float* src = (i < n4h) ? wv : wm;
    int j = (i < n4h) ? i : i - n4h;
    float4 f = ((const float4*)src)[j];
    ushort4 o;
    o.x = f2h(f.x); o.y = f2h(f.y); o.z = f2h(f.z); o.w = f2h(f.w);
    ((ushort4*)Wc)[i] = o;
}

// ---- per-node projection precompute ----
// Ph[node][512] f16:  [nhalf=0: sender-part val/gate (bias folded) | nhalf=1: receiver-part]
// within each 256-half: channel c in [0,128), packed pairs (val_c, gate_c) at c*2 + vg
__global__ void __launch_bounds__(THREADS, 4)
pcompute(const float* __restrict__ x,
         const unsigned short* __restrict__ Wc,
         const float* __restrict__ bval,
         const float* __restrict__ bmul,
         unsigned short* __restrict__ Ph)
{
    __shared__ unsigned short Xs[BN * SX];   // 17408 B
    const int tid  = threadIdx.x;
    const int n0   = blockIdx.x * BN;
    const int lane = tid & 63;
    const int wid  = tid >> 6;
    const int wm   = wid & 1;     // M half: rows [wm*32, wm*32+32)
    const int wn   = wid >> 1;    // 0..3: 64-wide N strip
    const int q    = lane >> 4;
    const int l16  = lane & 15;

    // stage x rows (128 f32 each) -> f16 LDS
#pragma unroll
    for (int i = 0; i < 2; ++i) {
        int u = tid + i * THREADS;          // 0..1023
        int row = u >> 4, seg = u & 15;     // 16 segs of 8 floats
        int node = n0 + row;
        if (node >= NN_NODES) node = NN_NODES - 1;
        const float* s = x + (size_t)node * NODE_DIM + seg * 8;
        float4 f0 = ((const float4*)s)[0];
        float4 f1 = ((const float4*)s)[1];
        uint4 v;
        v.x = (unsigned)f2h(f0.x) | ((unsigned)f2h(f0.y) << 16);
        v.y = (unsigned)f2h(f0.z) | ((unsigned)f2h(f0.w) << 16);
        v.z = (unsigned)f2h(f1.x) | ((unsigned)f2h(f1.y) << 16);
        v.w = (unsigned)f2h(f1.z) | ((unsigned)f2h(f1.w) << 16);
        *(uint4*)(&Xs[row * SX + seg * 8]) = v;
    }
    __syncthreads();

#pragma unroll
    for (int nhalf = 0; nhalf < 2; ++nhalf) {
        f32x4 acc[2][4];
        const f32x4 zero4 = {0.f, 0.f, 0.f, 0.f};
#pragma unroll
        for (int mt = 0; mt < 2; ++mt)
#pragma unroll
            for (int nt = 0; nt < 4; ++nt) acc[mt][nt] = zero4;

#pragma unroll
        for (int ks = 0; ks < 4; ++ks) {
            half8 a[2], b[4];
#pragma unroll
            for (int mt = 0; mt < 2; ++mt)
                a[mt] = *(const half8*)(&Xs[(wm * 32 + mt * 16 + l16) * SX + ks * 32 + q * 8]);
#pragma unroll
            for (int nt = 0; nt < 4; ++nt)
                b[nt] = *(const half8*)(Wc + (size_t)(wn * 64 + nt * 16 + l16) * KDIM
                                           + nhalf * 128 + ks * 32 + q * 8);
#pragma unroll
            for (int mt = 0; mt < 2; ++mt)
#pragma unroll
                for (int nt = 0; nt < 4; ++nt)
                    acc[mt][nt] = __builtin_amdgcn_mfma_f32_16x16x32_f16(
                        a[mt], b[nt], acc[mt][nt], 0, 0, 0);
        }

#pragma unroll
        for (int mt = 0; mt < 2; ++mt) {
#pragma unroll
            for (int nt = 0; nt < 4; ++nt) {
                int j  = wn * 64 + nt * 16 + l16;   // output channel in [0,256)
                int c  = j & 127;
                int vg = j >> 7;
                float bb = 0.f;
                if (nhalf == 0) bb = vg ? bmul[c] : bval[c];
#pragma unroll
                for (int r = 0; r < 4; ++r) {
                    int node = n0 + wm * 32 + mt * 16 + q * 4 + r;
                    if (node < NN_NODES)
                        Ph[(size_t)node * 512 + nhalf * 256 + c * 2 + vg] =
                            f2h(acc[mt][nt][r] + bb);
                }
            }
        }
    }
}

// ---- main: ef-GEMM (K=64) + gather-add node projections + activation + atomic scatter ----
__global__ void __launch_bounds__(THREADS, 4)
cgc_main(const unsigned short* __restrict__ Ph,   // [NN][512] f16
         const int* __restrict__ ei,              // [2][E]
         const float* __restrict__ ef,            // [E][64] fp32
         const unsigned short* __restrict__ Wc,   // [256][320] f16
         float* __restrict__ out)                 // [NN][128] fp32 (zeroed)
{
    __shared__ unsigned short As[BM * SA];        // 9216 B
    __shared__ int sIdx[BM];
    __shared__ int rIdx[BM];

    const int tid  = threadIdx.x;
    const int e0   = blockIdx.x * BM;
    const int lane = tid & 63;
    const int wid  = tid >> 6;
    const int wm   = wid & 1;     // rows [wm*32, wm*32+32)
    const int wn   = wid >> 1;    // 0..3: 32-col strip (val) + paired gate strip
    const int q    = lane >> 4;
    const int l16  = lane & 15;

    if (tid < BM) {
        sIdx[tid] = ei[e0 + tid];
        rIdx[tid] = ei[E_EDGES + e0 + tid];
    }

    // stage ef: 64 rows x 64 f32 -> f16, one chunk, 1 unit (8 floats) per thread
    {
        int row = tid >> 3, seg = tid & 7;
        const float* s = ef + (size_t)(e0 + row) * EDGE_DIM + seg * 8;
        float4 f0 = ((const float4*)s)[0];
        float4 f1 = ((const float4*)s)[1];
        uint4 v;
        v.x = (unsigned)f2h(f0.x) | ((unsigned)f2h(f0.y) << 16);
        v.y = (unsigned)f2h(f0.z) | ((unsigned)f2h(f0.w) << 16);
        v.z = (unsigned)f2h(f1.x) | ((unsigned)f2h(f1.y) << 16);
        v.w = (unsigned)f2h(f1.z) | ((unsigned)f2h(f1.w) << 16);
        *(uint4*)(&As[row * SA + seg * 8]) = v;
    }

    // B fragments straight from L2-resident Wc (edge-feature K-slice k=256..319),
    // issued before the barrier so the loads overlap the LDS staging drain.
    const int nb0 = wn * 32;
    const int nbase[4] = { nb0, nb0 + 16, 128 + nb0, 128 + nb0 + 16 };
    half8 b[2][4];
#pragma unroll
    for (int ks = 0; ks < 2; ++ks)
#pragma unroll
        for (int nt = 0; nt < 4; ++nt)
            b[ks][nt] = *(const half8*)(Wc + (size_t)(nbase[nt] + l16) * KDIM
                                           + 256 + ks * 32 + q * 8);

    f32x4 acc[2][4];
    const f32x4 zero4 = {0.f, 0.f, 0.f, 0.f};
#pragma unroll
    for (int mt = 0; mt < 2; ++mt)
#pragma unroll
        for (int nt = 0; nt < 4; ++nt) acc[mt][nt] = zero4;

    __syncthreads();

#pragma unroll
    for (int ks = 0; ks < 2; ++ks) {
        half8 a[2];
#pragma unroll
        for (int mt = 0; mt < 2; ++mt)
            a[mt] = *(const half8*)(&As[(wm * 32 + mt * 16 + l16) * SA + ks * 32 + q * 8]);
#pragma unroll
        for (int mt = 0; mt < 2; ++mt)
#pragma unroll
            for (int nt = 0; nt < 4; ++nt)
                acc[mt][nt] = __builtin_amdgcn_mfma_f32_16x16x32_f16(
                    a[mt], b[ks][nt], acc[mt][nt], 0, 0, 0);
    }

    // epilogue: add sender/receiver projections (bias folded into sender side),
    // softplus(val)*sigmoid(gate), atomic scatter by receiver.
#pragma unroll
    for (int mt = 0; mt < 2; ++mt) {
#pragma unroll
        for (int r = 0; r < 4; ++r) {
            int row = wm * 32 + mt * 16 + q * 4 + r;   // local edge row
            int sN = sIdx[row];
            int rN = rIdx[row];
            const unsigned* pS = (const unsigned*)(Ph + (size_t)sN * 512);        // sender half
            const unsigned* pR = (const unsigned*)(Ph + (size_t)rN * 512 + 256);  // receiver half
#pragma unroll
            for (int ct = 0; ct < 2; ++ct) {
                int c = wn * 32 + ct * 16 + l16;       // msg channel in [0,128)
                unsigned us = pS[c];                   // (val_s, gate_s) f16 pair
                unsigned ur = pR[c];                   // (val_r, gate_r) f16 pair
                float v = acc[mt][ct][r]     + h2f((unsigned short)(us & 0xffff))
                                             + h2f((unsigned short)(ur & 0xffff));
                float g = acc[mt][ct + 2][r] + h2f((unsigned short)(us >> 16))
                                             + h2f((unsigned short)(ur >> 16));
                float sp  = fmaxf(v, 0.f) + __logf(1.f + __expf(-fabsf(v)));
                float sig = __builtin_amdgcn_rcpf(1.f + __expf(-g));
                atomicAdd(out + (size_t)rN * NODE_DIM + c, sp * sig);
            }
        }
    }
}

// ============================ FALLBACK PATH (verified 598 us) ============================

__global__ void cast_all_kernel(const float* __restrict__ x,
                                const float* __restrict__ wv,
                                const float* __restrict__ wm,
                                unsigned short* __restrict__ xh,
                                unsigned short* __restrict__ wc) {
    const int n4x = (NN_NODES * NODE_DIM) / 4;        // 1,600,000
    const int n4h = (NODE_DIM * KDIM) / 4;            // 10,240
    int i = blockIdx.x * blockDim.x + threadIdx.x;
    if (i < n4x) {
        float4 f = ((const float4*)x)[i];
        ushort4 o;
        o.x = f2h(f.x); o.y = f2h(f.y); o.z = f2h(f.z); o.w = f2h(f.w);
        ((ushort4*)xh)[i] = o;
    } else {
        int k = i - n4x;
        if (k >= 2 * n4h) return;
        const float* src = (k < n4h) ? wv : wm;
        int j = (k < n4h) ? k : k - n4h;
        float4 f = ((const float4*)src)[j];
        ushort4 o;
        o.x = f2h(f.x); o.y = f2h(f.y); o.z = f2h(f.z); o.w = f2h(f.w);
        ((ushort4*)wc)[k] = o;
    }
}

__global__ void __launch_bounds__(THREADS, 4)
cgc_fallback(const unsigned short* __restrict__ xh,   // [NN][128] f16 bits
             const int* __restrict__ ei,              // [2][E]
             const float* __restrict__ ef,            // [E][64] fp32
             const unsigned short* __restrict__ Wc,   // [256][320] f16 bits
             const float* __restrict__ bval,          // [128]
             const float* __restrict__ bmul,          // [128]
             float* __restrict__ out)                 // [NN][128] fp32 (zeroed)
{
    __shared__ unsigned short As[OBM * SA];    // 18432 B
    __shared__ unsigned short Bs[NTOT * SA];   // 36864 B
    __shared__ int sIdx[OBM];
    __shared__ int rIdx[OBM];

    const int tid  = threadIdx.x;
    const int e0   = blockIdx.x * OBM;
    const int lane = tid & 63;
    const int wid  = tid >> 6;      // 0..7
    const int wm   = wid & 1;       // M half: rows [wm*64, wm*64+64)
    const int wn   = wid >> 1;      // 0..3: N strip of 32 output cols
    const int q    = lane >> 4;     // quad
    const int l16  = lane & 15;

    if (tid < OBM) {
        sIdx[tid] = ei[e0 + tid];
        rIdx[tid] = ei[E_EDGES + e0 + tid];
    }

    f32x4 acc[4][4];
    const f32x4 zero4 = {0.f, 0.f, 0.f, 0.f};
#pragma unroll
    for (int mt = 0; mt < 4; ++mt)
#pragma unroll
        for (int nt = 0; nt < 4; ++nt) acc[mt][nt] = zero4;

    for (int c = 0; c < 5; ++c) {
        __syncthreads();
        if (c < 4) {
            const int kcol = (c & 1) * 64;
#pragma unroll
            for (int i = 0; i < 2; ++i) {
                int u = tid + i * THREADS;
                int row = u >> 3, seg = u & 7;
                int node = (c < 2) ? sIdx[row] : rIdx[row];
                uint4 v = *(const uint4*)(xh + (size_t)node * NODE_DIM + kcol + seg * 8);
                *(uint4*)(&As[row * SA + seg * 8]) = v;
            }
        } else {
#pragma unroll
            for (int i = 0; i < 2; ++i) {
                int u = tid + i * THREADS;
                int row = u >> 3, seg = u & 7;
                const float* s = ef + (size_t)(e0 + row) * EDGE_DIM + seg * 8;
                float4 f0 = ((const float4*)s)[0];
                float4 f1 = ((const float4*)s)[1];
                uint4 v;
                v.x = (unsigned)f2h(f0.x) | ((unsigned)f2h(f0.y) << 16);
                v.y = (unsigned)f2h(f0.z) | ((unsigned)f2h(f0.w) << 16);
                v.z = (unsigned)f2h(f1.x) | ((unsigned)f2h(f1.y) << 16);
                v.w = (unsigned)f2h(f1.z) | ((unsigned)f2h(f1.w) << 16);
                *(uint4*)(&As[row * SA + seg * 8]) = v;
            }
        }
        {
            const int kOff = c * 64;
#pragma unroll
            for (int i = 0; i < 4; ++i) {
                int u = tid + i * THREADS;
                int n = u >> 3, seg = u & 7;
                uint4 v = *(const uint4*)(Wc + n * KDIM + kOff + seg * 8);
                *(uint4*)(&Bs[n * SA + seg * 8]) = v;
            }
        }
        __syncthreads();
#pragma unroll
        for (int ks = 0; ks < 64; ks += 32) {
            half8 a[4], b[4];
#pragma unroll
            for (int mt = 0; mt < 4; ++mt)
                a[mt] = *(const half8*)(&As[(wm * 64 + mt * 16 + l16) * SA + ks + q * 8]);
            const int nb0 = wn * 32;
            const int nbase[4] = { nb0, nb0 + 16, 128 + nb0, 128 + nb0 + 16 };
#pragma unroll
            for (int nt = 0; nt < 4; ++nt)
                b[nt] = *(const half8*)(&Bs[(nbase[nt] + l16) * SA + ks + q * 8]);
#pragma unroll
            for (int mt = 0; mt < 4; ++mt)
#pragma unroll
                for (int nt = 0; nt < 4; ++nt)
                    acc[mt][nt] = __builtin_amdgcn_mfma_f32_16x16x32_f16(
                        a[mt], b[nt], acc[mt][nt], 0, 0, 0);
        }
    }

#pragma unroll
    for (int ct = 0; ct < 2; ++ct) {
        const int col = wn * 32 + ct * 16 + l16;
        const float bv = bval[col];
        const float bm = bmul[col];
#pragma unroll
        for (int mt = 0; mt < 4; ++mt) {
#pragma unroll
            for (int r = 0; r < 4; ++r) {
                float v = acc[mt][ct][r] + bv;
                float g = acc[mt][ct + 2][r] + bm;
                float sp  = fmaxf(v, 0.f) + __logf(1.f + __expf(-fabsf(v)));
                float sig = __builtin_amdgcn_rcpf(1.f + __expf(-g));
                float msg = sp * sig;
                int rl = wm * 64 + mt * 16 + q * 4 + r;
                int node = rIdx[rl];
                atomicAdd(out + (size_t)node * NODE_DIM + col, msg);
            }
        }
    }
}

// ============================ LAUNCH ============================

extern "C" void kernel_launch(void* const* d_in, const int* in_sizes, int n_in,
                              void* d_out, int out_size, void* d_ws, size_t ws_size,
                              hipStream_t stream) {
    const float* x  = (const float*)d_in[0];
    const int*   ei = (const int*)d_in[1];
    const float* ef = (const float*)d_in[2];
    const float* Wv = (const float*)d_in[3];
    const float* bv = (const float*)d_in[4];
    const float* Wm = (const float*)d_in[5];
    const float* bm = (const float*)d_in[6];
    float* out = (float*)d_out;

    hipMemsetAsync(d_out, 0, (size_t)NN_NODES * NODE_DIM * sizeof(float), stream);

    const size_t need_new = 262144 + (size_t)NN_NODES * 512 * sizeof(unsigned short); // ~51.5 MB

    if (ws_size >= need_new) {
        // ---- new path: per-node projection precompute + K=64 edge GEMM ----
        unsigned short* Wc = (unsigned short*)d_ws;                       // 160 KB
        unsigned short* Ph = (unsigned short*)((char*)d_ws + 262144);     // 51.2 MB

        const int n4w = (2 * NODE_DIM * KDIM) / 4;   // 20480
        cast_w<<<(n4w + 255) / 256, 256, 0, stream>>>(Wv, Wm, Wc);
        pcompute<<<(NN_NODES + BN - 1) / BN, THREADS, 0, stream>>>(x, Wc, bv, bm, Ph);
        cgc_main<<<E_EDGES / BM, THREADS, 0, stream>>>(Ph, ei, ef, Wc, out);
    } else {
        // ---- fallback: verified single-pass kernel (13 MB workspace) ----
        unsigned short* xh = (unsigned short*)d_ws;                        // 12.8 MB
        unsigned short* Wc = (unsigned short*)((char*)d_ws + 12800000);    // 160 KB

        const int n4x = (NN_NODES * NODE_DIM) / 4;            // 1,600,000
        const int n4w = (2 * NODE_DIM * KDIM) / 4;            // 20,480
        const int total = n4x + n4w;
        cast_all_kernel<<<(total + 255) / 256, 256, 0, stream>>>(x, Wv, Wm, xh, Wc);
        cgc_fallback<<<E_EDGES / OBM, THREADS, 0, stream>>>(xh, ei, ef, Wc, bv, bm, out);
    }
}